// Round 15
// baseline (2247.661 us; speedup 1.0000x reference)
//
#include <hip/hip_runtime.h>
#include <hip/hip_bf16.h>
#include <stdint.h>

typedef __attribute__((ext_vector_type(8))) short short8;
typedef __attribute__((ext_vector_type(4))) float floatx4;
typedef __attribute__((ext_vector_type(4))) unsigned int uintx4;
typedef __attribute__((ext_vector_type(4))) unsigned short ushort4v;

#define DEVI __device__ __forceinline__

// ---- problem sizes ----
constexpr int B_ = 256, T_ = 512, D_ = 128, H_ = 512, C_ = 10;
constexpr int KTOT = H_ + D_;       // 640: k = [h(512) ; x(128)]
constexpr int RG = 16;              // batch rows per group
constexpr int NBG = 16;             // batch groups (8 pairs x 2)
constexpr int NCG = 16;             // column groups
constexpr int HCW = 32;             // h-cols per WG

// ---- workspace layout (bytes) ----
constexpr size_t OFF_XB = 0;
constexpr size_t SZ_XB  = (size_t)B_ * T_ * D_ * 2;          // x in bf16
constexpr size_t OFF_WC = OFF_XB + SZ_XB;
constexpr size_t SZ_WC  = (size_t)4 * H_ * KTOT * 2;         // Wcomb[4*H][640] bf16
constexpr size_t OFF_HB = OFF_WC + SZ_WC;
constexpr size_t SZ_HB  = (size_t)2 * B_ * H_ * 2;           // h double buffer bf16
constexpr size_t OFF_FL = OFF_HB + SZ_HB;
constexpr size_t SZ_FL  = (size_t)NBG * NCG * 64;            // flags: 64B apart
constexpr size_t WS_NEED = OFF_FL + SZ_FL;

DEVI uint16_t f2bf(float f) {
    uint32_t u = __builtin_bit_cast(uint32_t, f);
    u += 0x7FFFu + ((u >> 16) & 1u);
    return (uint16_t)(u >> 16);
}
DEVI float bf2f(uint16_t u) {
    return __builtin_bit_cast(float, (uint32_t)u << 16);
}
DEVI float sigf(float x)  { return 1.0f / (1.0f + __expf(-x)); }
DEVI float tanhf_(float x){ return 1.0f - 2.0f / (1.0f + __expf(2.0f * x)); }

// ---- prep: x fp32 -> bf16 ----
__global__ void k_cvt_x(const float* __restrict__ x, uint16_t* __restrict__ xb) {
    int i = (blockIdx.x * 256 + threadIdx.x) * 4;
    float4 v = *reinterpret_cast<const float4*>(x + i);
    ushort4v o;
    o.x = f2bf(v.x); o.y = f2bf(v.y); o.z = f2bf(v.z); o.w = f2bf(v.w);
    *reinterpret_cast<ushort4v*>(xb + i) = o;
}

// ---- prep: build combined transposed bf16 weights Wcomb[n'=g*512+n][k] ----
__global__ void k_build_w(const float* __restrict__ wgh, const float* __restrict__ wih,
                          const float* __restrict__ wfh, const float* __restrict__ woh,
                          const float* __restrict__ wgx, const float* __restrict__ wix,
                          const float* __restrict__ wfx, const float* __restrict__ wox,
                          uint16_t* __restrict__ wc) {
    int np = blockIdx.x;            // 0..2047
    int g = np >> 9, n = np & 511;
    const float* wh = (g == 0) ? wgh : (g == 1) ? wih : (g == 2) ? wfh : woh;
    const float* wx = (g == 0) ? wgx : (g == 1) ? wix : (g == 2) ? wfx : wox;
    for (int k = threadIdx.x; k < KTOT; k += 256) {
        float v = (k < H_) ? wh[(size_t)k * H_ + n] : wx[(size_t)(k - H_) * H_ + n];
        wc[(size_t)np * KTOT + k] = f2bf(v);
    }
}

// Opaque 16B weight load (resident in unified VGPR/AGPR file)
#define WLOAD(dst, base, IMM) \
    asm volatile("global_load_dwordx4 %0, %1, off offset:" #IMM \
                 : "=v"(dst) : "v"(base))
#define WLOAD20(arr, base) \
    WLOAD(arr[0],  base, 0);    WLOAD(arr[1],  base, 64);   \
    WLOAD(arr[2],  base, 128);  WLOAD(arr[3],  base, 192);  \
    WLOAD(arr[4],  base, 256);  WLOAD(arr[5],  base, 320);  \
    WLOAD(arr[6],  base, 384);  WLOAD(arr[7],  base, 448);  \
    WLOAD(arr[8],  base, 512);  WLOAD(arr[9],  base, 576);  \
    WLOAD(arr[10], base, 640);  WLOAD(arr[11], base, 704);  \
    WLOAD(arr[12], base, 768);  WLOAD(arr[13], base, 832);  \
    WLOAD(arr[14], base, 896);  WLOAD(arr[15], base, 960);  \
    WLOAD(arr[16], base, 1024); WLOAD(arr[17], base, 1088); \
    WLOAD(arr[18], base, 1152); WLOAD(arr[19], base, 1216)

// device-coherent 16B load (h exchange)
#define HLOAD(dst, base, IMM) \
    asm volatile("global_load_dwordx4 %0, %1, off offset:" #IMM " sc0 sc1" \
                 : "=v"(dst) : "v"(base) : "memory")
// cached 16B load (x prefetch; read-only data)
#define XLOAD(dst, base) \
    asm volatile("global_load_dwordx4 %0, %1, off" \
                 : "=v"(dst) : "v"(base) : "memory")
// device-coherent 4B store (h / flags)
#define DSTORE(addr, val) \
    asm volatile("global_store_dword %0, %1, off sc0 sc1" \
                 :: "v"(addr), "v"(val) : "memory")
// device-coherent 4B load (flag poll)
#define FLOAD(dst, addr) \
    asm volatile("global_load_dword %0, %1, off sc0 sc1" \
                 : "=v"(dst) : "v"(addr) : "memory")
#define WAITN(n) asm volatile("s_waitcnt vmcnt(" #n ")" ::: "memory")

// ---- main recurrent kernel ----
// 128 WGs; WG = (pair p, cg): TWO batch groups bgA=2p, bgB=2p+1, 16 rows each,
// same 32 h-cols (same weights+biases). Per step: compute A, compute B, ONE
// drain, post both flags, poll both flag sets, PREFETCH both groups' h(t+1)
// and x(t+1) into regs (consumed next iter -> load latency hidden).
// In-loop VMEM is all inline-asm with counted vmcnt (in-order retirement):
//   iter-boundary outstanding = [A4,xA,B4,xB] (10 loads)
//   stage A:  vmcnt(5)  (A4+xA landed; B set may fly)
//   stage B:  vmcnt(1)  (B4+xB landed; storeA may fly)
//   pre-flag: vmcnt(0)  (storeA old + storeB fresh drained)
// Producer/consumer semantics per group identical to validated r8.
__global__ __launch_bounds__(256, 1) void k_lstm(
    const uint16_t* __restrict__ xb,   // [B][T][D] bf16
    const uint16_t* __restrict__ wc,   // [4H][KTOT] bf16
    const float* __restrict__ bgp, const float* __restrict__ bip,
    const float* __restrict__ bfp, const float* __restrict__ bop,
    uint16_t* hbuf,                    // [2][B][H] bf16
    int* flags)                        // [NBG][NCG] ints, 64B apart
{
    __shared__ __align__(16) char hxA[RG * KTOT * 2];             // 20 KB
    __shared__ __align__(16) char hxB[RG * KTOT * 2];             // 20 KB
    __shared__ float preA[4][RG][HCW + 1];                        // 8448 B
    __shared__ float preB[4][RG][HCW + 1];                        // 8448 B

    const int tid  = threadIdx.x;
    const int lane = tid & 63;
    const int w    = tid >> 6;          // wave id == gate id
    const int bid  = blockIdx.x;        // 0..127
    const int p   = bid & 7;            // pair -> XCD p (perf heuristic only)
    const int cg  = bid >> 3;           // 0..15
    const int bgA = 2 * p, bgB = 2 * p + 1;
    const int b0A = bgA * RG, b0B = bgB * RG;
    const int hc0 = cg * HCW;

    // ---- weights (shared by A and B): r8-proven 160 regs/wave ----
    short8 bfr0[20], bfr1[20];
    {
        const int lcol = lane & 15, kgrp = lane >> 4;
        const uint16_t* src0 = wc + (size_t)(w * H_ + hc0 + 0  + lcol) * KTOT + kgrp * 8;
        const uint16_t* src1 = wc + (size_t)(w * H_ + hc0 + 16 + lcol) * KTOT + kgrp * 8;
        WLOAD20(bfr0, src0);
        WLOAD20(bfr1, src1);
        asm volatile("s_waitcnt vmcnt(0)" ::: "memory");
    }

    // ---- elementwise mapping (r8) ----
    const int erow = tid >> 4;
    const int epr  = tid & 15;
    const int hcg0 = hc0 + epr * 2;
    float bge[2], bie[2], bfe[2], boe[2];
    float cstA[2] = {0.f, 0.f}, cstB[2] = {0.f, 0.f};
    #pragma unroll
    for (int e = 0; e < 2; ++e) {
        bge[e] = bgp[hcg0 + e]; bie[e] = bip[hcg0 + e];
        bfe[e] = bfp[hcg0 + e]; boe[e] = bop[hcg0 + e];
    }

    // staging + A-frag mapping (r8)
    const int srow = tid >> 4, sseg = tid & 15;
    const int sswz = (srow & 7) << 4;
    const int arow = lane & 15, akg = lane >> 4;
    const int abase = arow * (KTOT * 2) + akg * 16;
    const int aswz  = (arow & 7) << 4;

    int* fslotA = flags + bgA * NCG * 16 + cg * 16;
    int* fslotB = flags + bgB * NCG * 16 + cg * 16;
    // poll addresses: lanes 0-15 -> A flags, lanes 16-31 -> B flags
    const int* pollp = (lane < 16) ? (flags + bgA * NCG * 16 + lane * 16)
                     : (flags + bgB * NCG * 16 + (lane & 15) * 16);

    // ---- prologue: stage zeros + x(0) into both LDS tiles ----
    {
        uintx4 z = {0u, 0u, 0u, 0u};
        #pragma unroll
        for (int c4 = 0; c4 < 4; ++c4) {
            int byte = srow * (KTOT * 2) + sseg * 64 + c4 * 16;
            *reinterpret_cast<uintx4*>(hxA + (byte ^ sswz)) = z;
            *reinterpret_cast<uintx4*>(hxB + (byte ^ sswz)) = z;
        }
        const short8 xvA = *reinterpret_cast<const short8*>(
            xb + ((size_t)(b0A + srow) * T_ + 0) * D_ + sseg * 8);
        const short8 xvB = *reinterpret_cast<const short8*>(
            xb + ((size_t)(b0B + srow) * T_ + 0) * D_ + sseg * 8);
        int byte = srow * (KTOT * 2) + H_ * 2 + sseg * 16;
        *reinterpret_cast<short8*>(hxA + (byte ^ sswz)) = xvA;
        *reinterpret_cast<short8*>(hxB + (byte ^ sswz)) = xvB;
    }
    __syncthreads();

    uintx4 hA0, hA1, hA2, hA3, xA;      // prefetch regs (A)
    uintx4 hB0, hB1, hB2, hB3, xB;      // prefetch regs (B)

    for (int t = 0; t < T_; ++t) {
        // ---- step0: stage LDS_A from prefetched regs ----
        if (t > 0) {
            WAITN(5);                    // A4 + xA landed (B set may still fly)
            #pragma unroll
            for (int c4 = 0; c4 < 4; ++c4) {
                uintx4 v = (c4 == 0) ? hA0 : (c4 == 1) ? hA1 : (c4 == 2) ? hA2 : hA3;
                int byte = srow * (KTOT * 2) + sseg * 64 + c4 * 16;
                *reinterpret_cast<uintx4*>(hxA + (byte ^ sswz)) = v;
            }
            int byte = srow * (KTOT * 2) + H_ * 2 + sseg * 16;
            *reinterpret_cast<uintx4*>(hxA + (byte ^ sswz)) = xA;
            __syncthreads();
        }

        // ---- step1: MFMA_A + pre_A + cell_A + store h_A(t+1) ----
        {
            floatx4 acc0 = {0.f, 0.f, 0.f, 0.f}, acc1 = {0.f, 0.f, 0.f, 0.f};
            #pragma unroll
            for (int ks = 0; ks < 20; ++ks) {
                int byte = (abase + ks * 64) ^ aswz;
                short8 a = *reinterpret_cast<const short8*>(hxA + byte);
                acc0 = __builtin_amdgcn_mfma_f32_16x16x32_bf16(a, bfr0[ks], acc0, 0, 0, 0);
                acc1 = __builtin_amdgcn_mfma_f32_16x16x32_bf16(a, bfr1[ks], acc1, 0, 0, 0);
            }
            #pragma unroll
            for (int r = 0; r < 4; ++r) {
                preA[w][(lane >> 4) * 4 + r][(lane & 15)]      = acc0[r];
                preA[w][(lane >> 4) * 4 + r][16 + (lane & 15)] = acc1[r];
            }
        }
        __syncthreads();
        {
            float hp[2];
            #pragma unroll
            for (int e = 0; e < 2; ++e) {
                int col = epr * 2 + e;
                float ag = preA[0][erow][col] + bge[e];
                float ai = preA[1][erow][col] + bie[e];
                float af = preA[2][erow][col] + bfe[e];
                float ao = preA[3][erow][col] + boe[e];
                float g = tanhf_(ag), ii = sigf(ai), f = sigf(af), o = sigf(ao);
                float c = g * ii + cstA[e] * f;
                cstA[e] = c;
                hp[e] = tanhf_(c) * o;
            }
            uint32_t packed = (uint32_t)f2bf(hp[0]) | ((uint32_t)f2bf(hp[1]) << 16);
            uint32_t* hdst = reinterpret_cast<uint32_t*>(
                hbuf + (size_t)((t + 1) & 1) * B_ * H_ + (size_t)(b0A + erow) * H_ + hcg0);
            DSTORE(hdst, packed);
        }

        // ---- step3: stage LDS_B from prefetched regs ----
        WAITN(1);                        // B4 + xB landed (storeA may still fly)
        if (t > 0) {
            #pragma unroll
            for (int c4 = 0; c4 < 4; ++c4) {
                uintx4 v = (c4 == 0) ? hB0 : (c4 == 1) ? hB1 : (c4 == 2) ? hB2 : hB3;
                int byte = srow * (KTOT * 2) + sseg * 64 + c4 * 16;
                *reinterpret_cast<uintx4*>(hxB + (byte ^ sswz)) = v;
            }
            int byte = srow * (KTOT * 2) + H_ * 2 + sseg * 16;
            *reinterpret_cast<uintx4*>(hxB + (byte ^ sswz)) = xB;
        }
        __syncthreads();

        // ---- step4: MFMA_B + pre_B + cell_B + store h_B(t+1) ----
        {
            floatx4 acc0 = {0.f, 0.f, 0.f, 0.f}, acc1 = {0.f, 0.f, 0.f, 0.f};
            #pragma unroll
            for (int ks = 0; ks < 20; ++ks) {
                int byte = (abase + ks * 64) ^ aswz;
                short8 a = *reinterpret_cast<const short8*>(hxB + byte);
                acc0 = __builtin_amdgcn_mfma_f32_16x16x32_bf16(a, bfr0[ks], acc0, 0, 0, 0);
                acc1 = __builtin_amdgcn_mfma_f32_16x16x32_bf16(a, bfr1[ks], acc1, 0, 0, 0);
            }
            #pragma unroll
            for (int r = 0; r < 4; ++r) {
                preB[w][(lane >> 4) * 4 + r][(lane & 15)]      = acc0[r];
                preB[w][(lane >> 4) * 4 + r][16 + (lane & 15)] = acc1[r];
            }
        }
        __syncthreads();
        {
            float hp[2];
            #pragma unroll
            for (int e = 0; e < 2; ++e) {
                int col = epr * 2 + e;
                float ag = preB[0][erow][col] + bge[e];
                float ai = preB[1][erow][col] + bie[e];
                float af = preB[2][erow][col] + bfe[e];
                float ao = preB[3][erow][col] + boe[e];
                float g = tanhf_(ag), ii = sigf(ai), f = sigf(af), o = sigf(ao);
                float c = g * ii + cstB[e] * f;
                cstB[e] = c;
                hp[e] = tanhf_(c) * o;
            }
            uint32_t packed = (uint32_t)f2bf(hp[0]) | ((uint32_t)f2bf(hp[1]) << 16);
            uint32_t* hdst = reinterpret_cast<uint32_t*>(
                hbuf + (size_t)((t + 1) & 1) * B_ * H_ + (size_t)(b0B + erow) * H_ + hcg0);
            DSTORE(hdst, packed);
        }

        // ---- step5: single drain, then post BOTH flags ----
        WAITN(0);                        // storeA (old) + storeB (fresh) at MALL
        __syncthreads();
        if (tid == 0) {
            DSTORE(fslotA, t + 1);
            DSTORE(fslotB, t + 1);
        }

        // ---- step6: poll both flag sets (wave0, lanes 0-31, one ballot) ----
        if (w == 0) {
            int it = 0;
            for (;;) {
                int f = t + 1;
                if (lane < 32) FLOAD(f, pollp);
                WAITN(0);
                if (__ballot(f >= t + 1) == ~0ull) break;
                if (++it > (1 << 22)) break;   // fail loud, not hang
            }
            asm volatile("" ::: "memory");
        }
        __syncthreads();

        // ---- step6.5: prefetch h(t+1) and x(t+1) for both groups ----
        {
            const int tn = (t + 1 < T_) ? (t + 1) : (T_ - 1);
            const uint16_t* hsA = hbuf + (size_t)((t + 1) & 1) * B_ * H_
                                       + (size_t)(b0A + srow) * H_ + sseg * 32;
            const uint16_t* xsA = xb + ((size_t)(b0A + srow) * T_ + tn) * D_ + sseg * 8;
            const uint16_t* hsB = hbuf + (size_t)((t + 1) & 1) * B_ * H_
                                       + (size_t)(b0B + srow) * H_ + sseg * 32;
            const uint16_t* xsB = xb + ((size_t)(b0B + srow) * T_ + tn) * D_ + sseg * 8;
            HLOAD(hA0, hsA, 0);  HLOAD(hA1, hsA, 16);
            HLOAD(hA2, hsA, 32); HLOAD(hA3, hsA, 48);
            XLOAD(xA, xsA);
            HLOAD(hB0, hsB, 0);  HLOAD(hB1, hsB, 16);
            HLOAD(hB2, hsB, 32); HLOAD(hB3, hsB, 48);
            XLOAD(xB, xsB);
            // no wait: consumed next iteration (step0 vmcnt(5) / step3 vmcnt(1))
        }
    }
}

// ---- final projection: out[b][c] = h_T[b] . wph[:,c] + bp[c] ----
__global__ void k_proj(const uint16_t* __restrict__ hb0, const float* __restrict__ wph,
                       const float* __restrict__ bp, float* __restrict__ out) {
    int b = blockIdx.x, lane = threadIdx.x;     // 64 threads
    const uint32_t* hrow = reinterpret_cast<const uint32_t*>(hb0 + (size_t)b * H_);
    float p[C_];
    #pragma unroll
    for (int c = 0; c < C_; ++c) p[c] = 0.f;
    #pragma unroll
    for (int q = 0; q < 4; ++q) {
        int k2 = lane + q * 64;
        uint32_t u = __hip_atomic_load(hrow + k2, __ATOMIC_RELAXED, __HIP_MEMORY_SCOPE_AGENT);
        float h0 = bf2f((uint16_t)(u & 0xFFFFu));
        float h1 = bf2f((uint16_t)(u >> 16));
        #pragma unroll
        for (int c = 0; c < C_; ++c)
            p[c] += h0 * wph[(size_t)(2 * k2) * C_ + c] + h1 * wph[(size_t)(2 * k2 + 1) * C_ + c];
    }
    #pragma unroll
    for (int c = 0; c < C_; ++c) {
        float v = p[c];
        #pragma unroll
        for (int off = 32; off; off >>= 1) v += __shfl_down(v, off, 64);
        if (lane == 0) out[(size_t)b * C_ + c] = v + bp[c];
    }
}

extern "C" void kernel_launch(void* const* d_in, const int* in_sizes, int n_in,
                              void* d_out, int out_size, void* d_ws, size_t ws_size,
                              hipStream_t stream) {
    const float* x   = (const float*)d_in[0];
    const float* wgx = (const float*)d_in[1];
    const float* wgh = (const float*)d_in[2];
    const float* bg  = (const float*)d_in[3];
    const float* wix = (const float*)d_in[4];
    const float* wih = (const float*)d_in[5];
    const float* bi  = (const float*)d_in[6];
    const float* wfx = (const float*)d_in[7];
    const float* wfh = (const float*)d_in[8];
    const float* bf  = (const float*)d_in[9];
    const float* wox = (const float*)d_in[10];
    const float* woh = (const float*)d_in[11];
    const float* bo  = (const float*)d_in[12];
    const float* wph = (const float*)d_in[13];
    const float* bp  = (const float*)d_in[14];

    if (ws_size < WS_NEED) return;  // fail loud (wrong output) rather than corrupt

    char* ws = (char*)d_ws;
    uint16_t* xbp = (uint16_t*)(ws + OFF_XB);
    uint16_t* wcp = (uint16_t*)(ws + OFF_WC);
    uint16_t* hbp = (uint16_t*)(ws + OFF_HB);
    int*      flp = (int*)(ws + OFF_FL);

    hipMemsetAsync(flp, 0, SZ_FL, stream);
    k_cvt_x<<<(B_ * T_ * D_) / (256 * 4), 256, 0, stream>>>(x, xbp);
    k_build_w<<<4 * H_, 256, 0, stream>>>(wgh, wih, wfh, woh, wgx, wix, wfx, wox, wcp);
    k_lstm<<<128, 256, 0, stream>>>(xbp, wcp, bg, bi, bf, bo, hbp, flp);
    k_proj<<<B_, 64, 0, stream>>>(hbp /* parity 0 holds h_T */, wph, bp, (float*)d_out);
}